// Round 1
// baseline (566.047 us; speedup 1.0000x reference)
//
#include <hip/hip_runtime.h>
#include <math.h>

// Problem constants (match setup_inputs)
#define BATCH 8
#define T_LEN 25000
#define NW    1000
#define WS    25
#define D0    256
#define H     128

typedef __bf16 bf16;
typedef bf16 bf16x8 __attribute__((ext_vector_type(8)));
typedef bf16 bf16x4 __attribute__((ext_vector_type(4)));
typedef float f32x4 __attribute__((ext_vector_type(4)));

__device__ __forceinline__ float gelu_exact(float x) {
    return 0.5f * x * (1.0f + erff(x * 0.70710678118654752f));
}

// ---------------------------------------------------------------------------
// Weight repack: fp32 (Cout=128, Cin, K) -> bf16 in MFMA A-fragment order:
//   dst[ ((k*KSn + ks)*8 + mt)*512 + lane*8 + j ]
//     = w[ co=mt*16+(lane&15) ][ ci=ks*32+(lane>>4)*8+j ][ k ]
// ---------------------------------------------------------------------------
__global__ void repack_w(const float* __restrict__ w, bf16* __restrict__ dst,
                         int Cin, int K, int KSn, int total) {
    int t = blockIdx.x * 256 + threadIdx.x;
    if (t >= total) return;
    int j    = t & 7;
    int lane = (t >> 3) & 63;
    int mt   = (t >> 9) & 7;
    int ks   = (t >> 12) % KSn;
    int k    = t / (4096 * KSn);
    int m = lane & 15, q = lane >> 4;
    int co = mt * 16 + m;
    int ci = ks * 32 + q * 8 + j;
    dst[t] = (bf16)w[(co * Cin + ci) * K + k];
}

// ---------------------------------------------------------------------------
// Fused critic: one block per (b, w) window. 256 threads = 4 waves.
// LDS layout (byte offsets into smem):
//   xT   bf16[38][264] @ 0      (rows = l+3, l in [-3,34]; conv0 input, bf16)
//   act3 float[128][26] @ 0     (overlay; conv2 output, fp32)
//   a1T  bf16[36][136] @ 20064  (rows = l+2, l in [-2,33])
//   a2T  bf16[36][136] @ 29856
//   feat float[128]    @ 39648
//   hbuf float[128]    @ 40160
// ---------------------------------------------------------------------------
#define XT_LD 264
#define A_LD  136
#define OFF_A1 20064
#define OFF_A2 29856
#define OFF_FEAT 39648
#define OFF_H    40160
#define SMEM_BYTES 40672

__global__ __launch_bounds__(256)
void critic_kernel(const float* __restrict__ lat,
                   const bf16* __restrict__ p0, const float* __restrict__ b0,
                   const bf16* __restrict__ p1, const float* __restrict__ b1,
                   const bf16* __restrict__ p2, const float* __restrict__ b2,
                   const float* __restrict__ hw1, const float* __restrict__ hb1,
                   const float* __restrict__ hw2, const float* __restrict__ hb2,
                   float* __restrict__ scores_tmp) {
    __shared__ __align__(16) char smem[SMEM_BYTES];
    bf16  (*xT)[XT_LD]  = (bf16(*)[XT_LD])smem;
    float (*act3)[26]   = (float(*)[26])smem;
    bf16  (*a1T)[A_LD]  = (bf16(*)[A_LD])(smem + OFF_A1);
    bf16  (*a2T)[A_LD]  = (bf16(*)[A_LD])(smem + OFF_A2);
    float* feat = (float*)(smem + OFF_FEAT);
    float* hbuf = (float*)(smem + OFF_H);

    const int tid = threadIdx.x;
    const int bx  = blockIdx.x;
    const int b   = bx / NW;
    const int w   = bx % NW;

    // ---- stage input window: lat[(b, w*25 + l, ci)] -> xT[l+3][ci] (bf16) ----
    {
        const float* src = lat + ((size_t)b * T_LEN + (size_t)w * WS) * D0;
        #pragma unroll
        for (int l = 0; l < WS; ++l)
            xT[l + 3][tid] = (bf16)src[l * D0 + tid];
        // zero pad rows of xT: r in {0,1,2} and {28..37}
        for (int i = tid; i < 13 * 256; i += 256) {
            int rr = i >> 8, c = i & 255;
            int r = (rr < 3) ? rr : (25 + rr);
            xT[r][c] = (bf16)0.0f;
        }
        // zero pad rows of a1T/a2T: r in {0,1} and {27..35}
        for (int i = tid; i < 11 * 128; i += 256) {
            int rr = i >> 7, c = i & 127;
            int r = (rr < 2) ? rr : (25 + rr);
            a1T[r][c] = (bf16)0.0f;
            a2T[r][c] = (bf16)0.0f;
        }
    }
    __syncthreads();

    const int lane = tid & 63, wv = tid >> 6;
    const int m = lane & 15, q = lane >> 4;

    // ================= conv0: Cin=256 (8 K-steps), K=7, pad=3 =================
    f32x4 acc[2][2] = {};
    {
        const bf16x8* A = (const bf16x8*)p0;
        for (int k = 0; k < 7; ++k) {
            #pragma unroll
            for (int ks = 0; ks < 8; ++ks) {
                bf16x8 a0 = A[((k * 8 + ks) * 8 + wv) * 64 + lane];
                bf16x8 a1 = A[((k * 8 + ks) * 8 + wv + 4) * 64 + lane];
                bf16x8 bb0 = *(const bf16x8*)&xT[m + k][ks * 32 + q * 8];
                bf16x8 bb1 = *(const bf16x8*)&xT[16 + m + k][ks * 32 + q * 8];
                acc[0][0] = __builtin_amdgcn_mfma_f32_16x16x32_bf16(a0, bb0, acc[0][0], 0, 0, 0);
                acc[0][1] = __builtin_amdgcn_mfma_f32_16x16x32_bf16(a0, bb1, acc[0][1], 0, 0, 0);
                acc[1][0] = __builtin_amdgcn_mfma_f32_16x16x32_bf16(a1, bb0, acc[1][0], 0, 0, 0);
                acc[1][1] = __builtin_amdgcn_mfma_f32_16x16x32_bf16(a1, bb1, acc[1][1], 0, 0, 0);
            }
        }
    }
    // epilogue: gelu -> a1T[l+2][co] (bf16), only real columns l<25
    #pragma unroll
    for (int mt = 0; mt < 2; ++mt) {
        int co0 = (wv + 4 * mt) * 16 + q * 4;
        #pragma unroll
        for (int nt = 0; nt < 2; ++nt) {
            int l = nt * 16 + m;
            if (l < 25) {
                bf16x4 v;
                #pragma unroll
                for (int r = 0; r < 4; ++r)
                    v[r] = (bf16)gelu_exact(acc[mt][nt][r] + b0[co0 + r]);
                *(bf16x4*)&a1T[l + 2][co0] = v;
            }
        }
    }
    __syncthreads();

    // ================= conv1: Cin=128 (4 K-steps), K=5, pad=2 =================
    f32x4 c1[2][2] = {};
    {
        const bf16x8* A = (const bf16x8*)p1;
        for (int k = 0; k < 5; ++k) {
            #pragma unroll
            for (int ks = 0; ks < 4; ++ks) {
                bf16x8 a0 = A[((k * 4 + ks) * 8 + wv) * 64 + lane];
                bf16x8 a1 = A[((k * 4 + ks) * 8 + wv + 4) * 64 + lane];
                bf16x8 bb0 = *(const bf16x8*)&a1T[m + k][ks * 32 + q * 8];
                bf16x8 bb1 = *(const bf16x8*)&a1T[16 + m + k][ks * 32 + q * 8];
                c1[0][0] = __builtin_amdgcn_mfma_f32_16x16x32_bf16(a0, bb0, c1[0][0], 0, 0, 0);
                c1[0][1] = __builtin_amdgcn_mfma_f32_16x16x32_bf16(a0, bb1, c1[0][1], 0, 0, 0);
                c1[1][0] = __builtin_amdgcn_mfma_f32_16x16x32_bf16(a1, bb0, c1[1][0], 0, 0, 0);
                c1[1][1] = __builtin_amdgcn_mfma_f32_16x16x32_bf16(a1, bb1, c1[1][1], 0, 0, 0);
            }
        }
    }
    #pragma unroll
    for (int mt = 0; mt < 2; ++mt) {
        int co0 = (wv + 4 * mt) * 16 + q * 4;
        #pragma unroll
        for (int nt = 0; nt < 2; ++nt) {
            int l = nt * 16 + m;
            if (l < 25) {
                bf16x4 v;
                #pragma unroll
                for (int r = 0; r < 4; ++r)
                    v[r] = (bf16)gelu_exact(c1[mt][nt][r] + b1[co0 + r]);
                *(bf16x4*)&a2T[l + 2][co0] = v;
            }
        }
    }
    __syncthreads();

    // ================= conv2: Cin=128 (4 K-steps), K=5, pad=2 =================
    f32x4 c2[2][2] = {};
    {
        const bf16x8* A = (const bf16x8*)p2;
        for (int k = 0; k < 5; ++k) {
            #pragma unroll
            for (int ks = 0; ks < 4; ++ks) {
                bf16x8 a0 = A[((k * 4 + ks) * 8 + wv) * 64 + lane];
                bf16x8 a1 = A[((k * 4 + ks) * 8 + wv + 4) * 64 + lane];
                bf16x8 bb0 = *(const bf16x8*)&a2T[m + k][ks * 32 + q * 8];
                bf16x8 bb1 = *(const bf16x8*)&a2T[16 + m + k][ks * 32 + q * 8];
                c2[0][0] = __builtin_amdgcn_mfma_f32_16x16x32_bf16(a0, bb0, c2[0][0], 0, 0, 0);
                c2[0][1] = __builtin_amdgcn_mfma_f32_16x16x32_bf16(a0, bb1, c2[0][1], 0, 0, 0);
                c2[1][0] = __builtin_amdgcn_mfma_f32_16x16x32_bf16(a1, bb0, c2[1][0], 0, 0, 0);
                c2[1][1] = __builtin_amdgcn_mfma_f32_16x16x32_bf16(a1, bb1, c2[1][1], 0, 0, 0);
            }
        }
    }
    __syncthreads();  // all a2T reads done before overwriting smem base (act3 overlays xT only, but keep order strict)
    // epilogue: gelu -> act3[co][l] (fp32, overlays xT region — xT dead since conv0)
    #pragma unroll
    for (int mt = 0; mt < 2; ++mt) {
        int co0 = (wv + 4 * mt) * 16 + q * 4;
        #pragma unroll
        for (int nt = 0; nt < 2; ++nt) {
            int l = nt * 16 + m;
            if (l < 25) {
                #pragma unroll
                for (int r = 0; r < 4; ++r)
                    act3[co0 + r][l] = gelu_exact(c2[mt][nt][r] + b2[co0 + r]);
            }
        }
    }
    __syncthreads();

    // ================= mean pool -> head =================
    if (tid < H) {
        float s = 0.0f;
        #pragma unroll
        for (int l = 0; l < WS; ++l) s += act3[tid][l];
        feat[tid] = s / 25.0f;
    }
    __syncthreads();

    if (tid < H) {
        const float* row = hw1 + tid * H;
        float a = hb1[tid];
        #pragma unroll 8
        for (int j = 0; j < H; ++j) a += row[j] * feat[j];
        hbuf[tid] = gelu_exact(a);
    }
    __syncthreads();

    if (tid < 64) {
        float p = hw2[tid] * hbuf[tid] + hw2[tid + 64] * hbuf[tid + 64];
        #pragma unroll
        for (int off = 32; off > 0; off >>= 1) p += __shfl_down(p, off);
        if (tid == 0) {
            float z = p + hb2[0];
            float sc = 5.0f / (1.0f + expf(-z));
            scores_tmp[bx] = sc;   // bx = b*NW + w
        }
    }
}

// ---------------------------------------------------------------------------
// finalize: scores[w] = mean_b tmp[b*NW+w]; out[w]=scores, out[NW+w]=(s<3.5)
// ---------------------------------------------------------------------------
__global__ void finalize_kernel(const float* __restrict__ tmp, float* __restrict__ out) {
    int w = blockIdx.x * 256 + threadIdx.x;
    if (w < NW) {
        float s = 0.0f;
        #pragma unroll
        for (int b = 0; b < BATCH; ++b) s += tmp[b * NW + w];
        s *= 0.125f;
        out[w] = s;
        out[NW + w] = (s < 3.5f) ? 1.0f : 0.0f;
    }
}

// ---------------------------------------------------------------------------
extern "C" void kernel_launch(void* const* d_in, const int* in_sizes, int n_in,
                              void* d_out, int out_size, void* d_ws, size_t ws_size,
                              hipStream_t stream) {
    const float* lat  = (const float*)d_in[0];
    const float* c0w  = (const float*)d_in[1];
    const float* c0b  = (const float*)d_in[2];
    const float* c1w  = (const float*)d_in[3];
    const float* c1b  = (const float*)d_in[4];
    const float* c2w  = (const float*)d_in[5];
    const float* c2b  = (const float*)d_in[6];
    const float* hw1  = (const float*)d_in[7];
    const float* hb1  = (const float*)d_in[8];
    const float* hw2  = (const float*)d_in[9];
    const float* hb2  = (const float*)d_in[10];

    // workspace layout
    bf16* p0 = (bf16*)d_ws;                                   // 229376 bf16 = 458752 B
    bf16* p1 = (bf16*)((char*)d_ws + 458752);                 //  81920 bf16 = 163840 B
    bf16* p2 = (bf16*)((char*)d_ws + 622592);                 //  81920 bf16 = 163840 B
    float* tmp = (float*)((char*)d_ws + 786432);              //   8000 fp32

    const int n0 = 128 * 256 * 7;  // 229376
    const int n1 = 128 * 128 * 5;  //  81920
    repack_w<<<(n0 + 255) / 256, 256, 0, stream>>>(c0w, p0, 256, 7, 8, n0);
    repack_w<<<(n1 + 255) / 256, 256, 0, stream>>>(c1w, p1, 128, 5, 4, n1);
    repack_w<<<(n1 + 255) / 256, 256, 0, stream>>>(c2w, p2, 128, 5, 4, n1);

    critic_kernel<<<BATCH * NW, 256, 0, stream>>>(lat, p0, c0b, p1, c1b, p2, c2b,
                                                  hw1, hb1, hw2, hb2, tmp);
    finalize_kernel<<<4, 256, 0, stream>>>(tmp, (float*)d_out);
}

// Round 2
// 537.632 us; speedup vs baseline: 1.0529x; 1.0529x over previous
//
#include <hip/hip_runtime.h>
#include <math.h>

// Problem constants (match setup_inputs)
#define BATCH 8
#define T_LEN 25000
#define NW    1000
#define WS    25
#define D0    256
#define H     128

typedef __bf16 bf16;
typedef bf16 bf16x8 __attribute__((ext_vector_type(8)));
typedef bf16 bf16x4 __attribute__((ext_vector_type(4)));
typedef float f32x4 __attribute__((ext_vector_type(4)));

// tanh-form GELU via v_exp_f32 (~12 VALU vs ~40 for divergent erff path).
// |gelu_tanh - gelu_exact| <= ~3e-3; downstream gain ~1.3/layer keeps us
// well under the 4.78e-2 threshold (round-1 absmax was 1.56e-2).
__device__ __forceinline__ float gelu_fast(float x) {
    float y = 0.7978845608f * x * (1.0f + 0.044715f * x * x);
    float e = __expf(2.0f * y);                    // v_exp_f32
    float t = 1.0f - 2.0f * __builtin_amdgcn_rcpf(e + 1.0f);  // tanh(y)
    return 0.5f * x * (1.0f + t);
}

// ---------------------------------------------------------------------------
// Weight repack: fp32 (Cout=128, Cin, K) -> bf16 in MFMA A-fragment order:
//   dst[ ((k*KSn + ks)*8 + mt)*512 + lane*8 + j ]
//     = w[ co=mt*16+(lane&15) ][ ci=ks*32+(lane>>4)*8+j ][ k ]
// ---------------------------------------------------------------------------
__global__ void repack_w(const float* __restrict__ w, bf16* __restrict__ dst,
                         int Cin, int K, int KSn, int total) {
    int t = blockIdx.x * 256 + threadIdx.x;
    if (t >= total) return;
    int j    = t & 7;
    int lane = (t >> 3) & 63;
    int mt   = (t >> 9) & 7;
    int ks   = (t >> 12) % KSn;
    int k    = t / (4096 * KSn);
    int m = lane & 15, q = lane >> 4;
    int co = mt * 16 + m;
    int ci = ks * 32 + q * 8 + j;
    dst[t] = (bf16)w[(co * Cin + ci) * K + k];
}

__global__ void cvt_bf16(const float* __restrict__ w, bf16* __restrict__ dst, int n) {
    int t = blockIdx.x * 256 + threadIdx.x;
    if (t < n) dst[t] = (bf16)w[t];
}

// ---------------------------------------------------------------------------
// Fused critic: one block per (b, w) window. 256 threads = 4 waves.
// Slim LDS (27200 B -> 6 blocks/CU by LDS; launch_bounds targets 6 w/EU):
//   R0  @0      : xT  bf16[32][264] (rows = l+3, l in [-3,28])  16896 B
//                 (a2T bf16[29][136] overlays R0 after conv0)
//   R1  @16896  : a1T bf16[29][136] (rows = l+2, l in [-2,26])   7888 B
//   feat @24784 : float[128]
//   hbuf @25296 : float[128]
//   tail pad to 27200 so garbage-column B-reads (rows beyond the real pad,
//   belonging to discarded l>=25 output columns) stay inside the allocation.
// ---------------------------------------------------------------------------
#define XT_LD 264
#define A_LD  136
#define OFF_A1   16896
#define OFF_FEAT 24784
#define OFF_H    25296
#define SMEM_BYTES 27200

__global__ __launch_bounds__(256, 6)
void critic_kernel(const float* __restrict__ lat,
                   const bf16* __restrict__ p0, const float* __restrict__ b0,
                   const bf16* __restrict__ p1, const float* __restrict__ b1,
                   const bf16* __restrict__ p2, const float* __restrict__ b2,
                   const bf16* __restrict__ hw1b, const float* __restrict__ hb1,
                   const float* __restrict__ hw2, const float* __restrict__ hb2,
                   float* __restrict__ scores_tmp) {
    __shared__ __align__(16) char smem[SMEM_BYTES];
    bf16  (*xT)[XT_LD]  = (bf16(*)[XT_LD])smem;
    bf16  (*a2T)[A_LD]  = (bf16(*)[A_LD])smem;           // overlays xT (dead after conv0)
    bf16  (*a1T)[A_LD]  = (bf16(*)[A_LD])(smem + OFF_A1);
    float* feat = (float*)(smem + OFF_FEAT);
    float* hbuf = (float*)(smem + OFF_H);

    const int tid = threadIdx.x;
    const int bx  = blockIdx.x;
    const int b   = bx / NW;
    const int w   = bx % NW;

    // ---- stage input window (vectorized float4 -> bf16x4) ----
    {
        const float4* src4 = (const float4*)(lat + ((size_t)b * T_LEN + (size_t)w * WS) * D0);
        #pragma unroll
        for (int it = 0; it < 7; ++it) {
            int g = tid + it * 256;       // 1600 float4s total
            if (g < 1600) {
                int l = g >> 6, c0 = (g & 63) * 4;
                float4 v = src4[g];
                bf16x4 o = {(bf16)v.x, (bf16)v.y, (bf16)v.z, (bf16)v.w};
                *(bf16x4*)&xT[l + 3][c0] = o;
            }
        }
        // zero xT pad rows {0,1,2,28,29,30,31} x 256 cols = 448 bf16x4
        bf16x4 z4 = {};
        #pragma unroll
        for (int it = 0; it < 2; ++it) {
            int i = tid + it * 256;
            if (i < 448) {
                int rr = i >> 6;
                int r = (rr < 3) ? rr : rr + 25;
                *(bf16x4*)&xT[r][(i & 63) * 4] = z4;
            }
        }
        // zero a1T pad rows {0,1,27,28} x 128 cols, same for a2T... but a2T
        // overlays xT (written later by conv1 epilogue). Its pad rows must be
        // zeroed AFTER conv0's xT reads; do it in conv0 epilogue phase below.
        {   // a1T pads: 4 rows x 128 = 128 bf16x4 -> threads 0..127
            if (tid < 128) {
                int rr = tid >> 5;
                int r = (rr < 2) ? rr : rr + 25;
                *(bf16x4*)&a1T[r][(tid & 31) * 4] = z4;
            }
        }
    }
    __syncthreads();

    const int lane = tid & 63, wv = tid >> 6;
    const int m = lane & 15, q = lane >> 4;
    const bf16* xbase  = &xT[m][q * 8];
    const bf16* a1base = &a1T[m][q * 8];

    // ================= conv0: Cin=256 (8 K-steps), K=7, pad=3 =================
    f32x4 acc[2][2] = {};
    {
        const bf16x8* A = (const bf16x8*)p0 + (size_t)wv * 64 + lane;
        #pragma unroll
        for (int k = 0; k < 7; ++k) {
            #pragma unroll
            for (int ks = 0; ks < 8; ++ks) {
                bf16x8 a0 = A[(k * 8 + ks) * 512];
                bf16x8 a1 = A[(k * 8 + ks) * 512 + 256];
                bf16x8 bb0 = *(const bf16x8*)(xbase + k * XT_LD + ks * 32);
                bf16x8 bb1 = *(const bf16x8*)(xbase + k * XT_LD + ks * 32 + 16 * XT_LD);
                acc[0][0] = __builtin_amdgcn_mfma_f32_16x16x32_bf16(a0, bb0, acc[0][0], 0, 0, 0);
                acc[0][1] = __builtin_amdgcn_mfma_f32_16x16x32_bf16(a0, bb1, acc[0][1], 0, 0, 0);
                acc[1][0] = __builtin_amdgcn_mfma_f32_16x16x32_bf16(a1, bb0, acc[1][0], 0, 0, 0);
                acc[1][1] = __builtin_amdgcn_mfma_f32_16x16x32_bf16(a1, bb1, acc[1][1], 0, 0, 0);
            }
        }
    }
    __syncthreads();   // all xT reads done; R0 may now be overwritten (a2T)
    // epilogue: gelu -> a1T[l+2][co]; also zero a2T pad rows (R0)
    {
        bf16x4 z4 = {};
        if (tid < 128) {
            int rr = tid >> 5;
            int r = (rr < 2) ? rr : rr + 25;
            *(bf16x4*)&a2T[r][(tid & 31) * 4] = z4;
        }
    }
    #pragma unroll
    for (int mt = 0; mt < 2; ++mt) {
        int co0 = (wv + 4 * mt) * 16 + q * 4;
        f32x4 bv = *(const f32x4*)&b0[co0];
        #pragma unroll
        for (int nt = 0; nt < 2; ++nt) {
            int l = nt * 16 + m;
            if (l < 25) {
                bf16x4 v;
                #pragma unroll
                for (int r = 0; r < 4; ++r)
                    v[r] = (bf16)gelu_fast(acc[mt][nt][r] + bv[r]);
                *(bf16x4*)&a1T[l + 2][co0] = v;
            }
        }
    }
    __syncthreads();

    // ================= conv1: Cin=128 (4 K-steps), K=5, pad=2 =================
    f32x4 c1[2][2] = {};
    {
        const bf16x8* A = (const bf16x8*)p1 + (size_t)wv * 64 + lane;
        #pragma unroll
        for (int k = 0; k < 5; ++k) {
            #pragma unroll
            for (int ks = 0; ks < 4; ++ks) {
                bf16x8 a0 = A[(k * 4 + ks) * 512];
                bf16x8 a1 = A[(k * 4 + ks) * 512 + 256];
                bf16x8 bb0 = *(const bf16x8*)(a1base + k * A_LD + ks * 32);
                bf16x8 bb1 = *(const bf16x8*)(a1base + k * A_LD + ks * 32 + 16 * A_LD);
                c1[0][0] = __builtin_amdgcn_mfma_f32_16x16x32_bf16(a0, bb0, c1[0][0], 0, 0, 0);
                c1[0][1] = __builtin_amdgcn_mfma_f32_16x16x32_bf16(a0, bb1, c1[0][1], 0, 0, 0);
                c1[1][0] = __builtin_amdgcn_mfma_f32_16x16x32_bf16(a1, bb0, c1[1][0], 0, 0, 0);
                c1[1][1] = __builtin_amdgcn_mfma_f32_16x16x32_bf16(a1, bb1, c1[1][1], 0, 0, 0);
            }
        }
    }
    // epilogue -> a2T (in R0; xT dead, conv1's own a1T reads already issued
    // before each wave's writes here; cross-wave overlap only touches
    // garbage-column rows whose outputs are discarded)
    #pragma unroll
    for (int mt = 0; mt < 2; ++mt) {
        int co0 = (wv + 4 * mt) * 16 + q * 4;
        f32x4 bv = *(const f32x4*)&b1[co0];
        #pragma unroll
        for (int nt = 0; nt < 2; ++nt) {
            int l = nt * 16 + m;
            if (l < 25) {
                bf16x4 v;
                #pragma unroll
                for (int r = 0; r < 4; ++r)
                    v[r] = (bf16)gelu_fast(c1[mt][nt][r] + bv[r]);
                *(bf16x4*)&a2T[l + 2][co0] = v;
            }
        }
    }
    __syncthreads();

    // ================= conv2: Cin=128 (4 K-steps), K=5, pad=2 =================
    f32x4 c2[2][2] = {};
    {
        const bf16* a2base = &a2T[m][q * 8];
        const bf16x8* A = (const bf16x8*)p2 + (size_t)wv * 64 + lane;
        #pragma unroll
        for (int k = 0; k < 5; ++k) {
            #pragma unroll
            for (int ks = 0; ks < 4; ++ks) {
                bf16x8 a0 = A[(k * 4 + ks) * 512];
                bf16x8 a1 = A[(k * 4 + ks) * 512 + 256];
                bf16x8 bb0 = *(const bf16x8*)(a2base + k * A_LD + ks * 32);
                bf16x8 bb1 = *(const bf16x8*)(a2base + k * A_LD + ks * 32 + 16 * A_LD);
                c2[0][0] = __builtin_amdgcn_mfma_f32_16x16x32_bf16(a0, bb0, c2[0][0], 0, 0, 0);
                c2[0][1] = __builtin_amdgcn_mfma_f32_16x16x32_bf16(a0, bb1, c2[0][1], 0, 0, 0);
                c2[1][0] = __builtin_amdgcn_mfma_f32_16x16x32_bf16(a1, bb0, c2[1][0], 0, 0, 0);
                c2[1][1] = __builtin_amdgcn_mfma_f32_16x16x32_bf16(a1, bb1, c2[1][1], 0, 0, 0);
            }
        }
    }
    // ===== register pooling epilogue: gelu + sum over l via lane shuffles =====
    // C-layout: col l = nt*16+m, row co = co0 + r. Reduce over m (lane bits 0-3).
    #pragma unroll
    for (int mt = 0; mt < 2; ++mt) {
        int co0 = (wv + 4 * mt) * 16 + q * 4;
        f32x4 bv = *(const f32x4*)&b2[co0];
        f32x4 pool;
        #pragma unroll
        for (int r = 0; r < 4; ++r) {
            float s = gelu_fast(c2[mt][0][r] + bv[r]);            // l = m < 25 always
            float g1 = gelu_fast(c2[mt][1][r] + bv[r]);           // l = 16+m
            s += (m < 9) ? g1 : 0.0f;
            s += __shfl_xor(s, 1);
            s += __shfl_xor(s, 2);
            s += __shfl_xor(s, 4);
            s += __shfl_xor(s, 8);
            pool[r] = s * 0.04f;                                  // /25
        }
        if (m == 0) *(f32x4*)&feat[co0] = pool;
    }
    __syncthreads();

    // ================= head: h = gelu(feat @ W1^T + b1) =================
    if (tid < H) {
        const bf16x8* row = (const bf16x8*)(hw1b + tid * H);
        float a = hb1[tid];
        #pragma unroll
        for (int jv = 0; jv < 16; ++jv) {
            bf16x8 w8 = row[jv];
            #pragma unroll
            for (int u = 0; u < 8; ++u)
                a += (float)w8[u] * feat[jv * 8 + u];
        }
        hbuf[tid] = gelu_fast(a);
    }
    __syncthreads();

    if (tid < 64) {
        float p = hw2[tid] * hbuf[tid] + hw2[tid + 64] * hbuf[tid + 64];
        #pragma unroll
        for (int off = 32; off > 0; off >>= 1) p += __shfl_down(p, off);
        if (tid == 0) {
            float z = p + hb2[0];
            scores_tmp[bx] = 5.0f / (1.0f + expf(-z));   // bx = b*NW + w
        }
    }
}

// ---------------------------------------------------------------------------
__global__ void finalize_kernel(const float* __restrict__ tmp, float* __restrict__ out) {
    int w = blockIdx.x * 256 + threadIdx.x;
    if (w < NW) {
        float s = 0.0f;
        #pragma unroll
        for (int b = 0; b < BATCH; ++b) s += tmp[b * NW + w];
        s *= 0.125f;
        out[w] = s;
        out[NW + w] = (s < 3.5f) ? 1.0f : 0.0f;
    }
}

// ---------------------------------------------------------------------------
extern "C" void kernel_launch(void* const* d_in, const int* in_sizes, int n_in,
                              void* d_out, int out_size, void* d_ws, size_t ws_size,
                              hipStream_t stream) {
    const float* lat  = (const float*)d_in[0];
    const float* c0w  = (const float*)d_in[1];
    const float* c0b  = (const float*)d_in[2];
    const float* c1w  = (const float*)d_in[3];
    const float* c1b  = (const float*)d_in[4];
    const float* c2w  = (const float*)d_in[5];
    const float* c2b  = (const float*)d_in[6];
    const float* hw1  = (const float*)d_in[7];
    const float* hb1  = (const float*)d_in[8];
    const float* hw2  = (const float*)d_in[9];
    const float* hb2  = (const float*)d_in[10];

    // workspace layout
    bf16* p0   = (bf16*)d_ws;                                 // 458752 B
    bf16* p1   = (bf16*)((char*)d_ws + 458752);               // 163840 B
    bf16* p2   = (bf16*)((char*)d_ws + 622592);               // 163840 B
    bf16* hw1b = (bf16*)((char*)d_ws + 786432);               //  32768 B
    float* tmp = (float*)((char*)d_ws + 819200);              //  32000 B

    const int n0 = 128 * 256 * 7;  // 229376
    const int n1 = 128 * 128 * 5;  //  81920
    repack_w<<<(n0 + 255) / 256, 256, 0, stream>>>(c0w, p0, 256, 7, 8, n0);
    repack_w<<<(n1 + 255) / 256, 256, 0, stream>>>(c1w, p1, 128, 5, 4, n1);
    repack_w<<<(n1 + 255) / 256, 256, 0, stream>>>(c2w, p2, 128, 5, 4, n1);
    cvt_bf16<<<64, 256, 0, stream>>>(hw1, hw1b, 128 * 128);

    critic_kernel<<<BATCH * NW, 256, 0, stream>>>(lat, p0, c0b, p1, c1b, p2, c2b,
                                                  hw1b, hb1, hw2, hb2, tmp);
    finalize_kernel<<<4, 256, 0, stream>>>(tmp, (float*)d_out);
}

// Round 3
// 504.463 us; speedup vs baseline: 1.1221x; 1.0658x over previous
//
#include <hip/hip_runtime.h>
#include <math.h>

// Problem constants (match setup_inputs)
#define BATCH 8
#define T_LEN 25000
#define NW    1000
#define WS    25
#define D0    256
#define H     128

typedef __bf16 bf16;
typedef bf16 bf16x8 __attribute__((ext_vector_type(8)));
typedef bf16 bf16x4 __attribute__((ext_vector_type(4)));
typedef float f32x4 __attribute__((ext_vector_type(4)));

// tanh-form GELU via v_exp_f32. |err| <= ~3e-3 absolute.
__device__ __forceinline__ float gelu_fast(float x) {
    float y = 0.7978845608f * x * (1.0f + 0.044715f * x * x);
    float e = __expf(2.0f * y);
    float t = 1.0f - 2.0f * __builtin_amdgcn_rcpf(e + 1.0f);
    return 0.5f * x * (1.0f + t);
}

// ---------------------------------------------------------------------------
// Weight repack: fp32 (Cout=128, Cin, K) -> bf16 in MFMA A-fragment order:
//   dst[ ((k*KSn + ks)*8 + mt)*512 + lane*8 + j ]
//     = w[ co=mt*16+(lane&15) ][ ci=ks*32+(lane>>4)*8+j ][ k ]
// ---------------------------------------------------------------------------
__global__ void repack_w(const float* __restrict__ w, bf16* __restrict__ dst,
                         int Cin, int K, int KSn, int total) {
    int t = blockIdx.x * 256 + threadIdx.x;
    if (t >= total) return;
    int j    = t & 7;
    int lane = (t >> 3) & 63;
    int mt   = (t >> 9) & 7;
    int ks   = (t >> 12) % KSn;
    int k    = t / (4096 * KSn);
    int m = lane & 15, q = lane >> 4;
    int co = mt * 16 + m;
    int ci = ks * 32 + q * 8 + j;
    dst[t] = (bf16)w[(co * Cin + ci) * K + k];
}

__global__ void cvt_bf16(const float* __restrict__ w, bf16* __restrict__ dst, int n) {
    int t = blockIdx.x * 256 + threadIdx.x;
    if (t < n) dst[t] = (bf16)w[t];
}

// ---------------------------------------------------------------------------
// Fused critic, W=2 windows per block (N=64 -> each A-load feeds 4 MFMAs,
// halving the per-window L2 weight stream). One block = 256 thr = 4 waves.
//
// LDS (50560 B -> 3 blocks/CU):
//  R0 @0     : xT bf16[62][264]; rows 0..30 = window A (l+3), 31..61 = B (l+9)
//              (a2T bf16[58][136] overlays R0 after conv0: rows 0..28 win A,
//               29..57 win B)
//  R1 @32736 : a1T bf16[58][136]; same row split as a2T
//  feat @48512 : float[256]  (128 per window)
//  hbuf @49536 : float[256]
// Garbage-column B-reads (discarded l>=25 output cols) over-read past each
// region; max offsets verified <= 50560 (conv1 worst: 50400). These lands are
// read-only and barrier-ordered vs later-phase writes.
// ---------------------------------------------------------------------------
#define XT_LD 264
#define A_LD  136
#define OFF_A1   32736
#define OFF_FEAT 48512
#define OFF_H    49536
#define SMEM_BYTES 50560

__global__ __launch_bounds__(256, 3)
void critic_kernel(const float* __restrict__ lat,
                   const bf16* __restrict__ p0, const float* __restrict__ b0,
                   const bf16* __restrict__ p1, const float* __restrict__ b1,
                   const bf16* __restrict__ p2, const float* __restrict__ b2,
                   const bf16* __restrict__ hw1b, const float* __restrict__ hb1,
                   const float* __restrict__ hw2, const float* __restrict__ hb2,
                   float* __restrict__ scores_tmp) {
    __shared__ __align__(16) char smem[SMEM_BYTES];
    bf16  (*xT)[XT_LD]  = (bf16(*)[XT_LD])smem;
    bf16  (*a2T)[A_LD]  = (bf16(*)[A_LD])smem;            // overlays xT after conv0
    bf16  (*a1T)[A_LD]  = (bf16(*)[A_LD])(smem + OFF_A1);
    float* feat = (float*)(smem + OFF_FEAT);
    float* hbuf = (float*)(smem + OFF_H);

    const int tid = threadIdx.x;
    const int bx  = blockIdx.x;
    const int b   = bx / (NW / 2);
    const int wi  = bx % (NW / 2);        // window pair index
    const int w0  = 2 * wi;

    // ---- stage 2 adjacent windows: 50*256 floats = 3200 float4 ----
    {
        const float4* src4 = (const float4*)(lat + ((size_t)b * T_LEN + (size_t)w0 * WS) * D0);
        #pragma unroll
        for (int it = 0; it < 12; ++it) {
            int g = tid + it * 256;
            int l = g >> 6, c0 = (g & 63) * 4;
            int r = (l < 25) ? (l + 3) : (l + 9);   // win B rows start at 31
            float4 v = src4[g];
            bf16x4 o = {(bf16)v.x, (bf16)v.y, (bf16)v.z, (bf16)v.w};
            *(bf16x4*)&xT[r][c0] = o;
        }
        {   // tail 128 float4s
            if (tid < 128) {
                int g = 3072 + tid;
                int l = g >> 6, c0 = (g & 63) * 4;
                int r = (l < 25) ? (l + 3) : (l + 9);
                float4 v = src4[g];
                bf16x4 o = {(bf16)v.x, (bf16)v.y, (bf16)v.z, (bf16)v.w};
                *(bf16x4*)&xT[r][c0] = o;
            }
        }
        // zero xT pad rows {0,1,2,28,29,30} + {31,32,33,59,60,61}: 12 rows
        bf16x4 z4 = {};
        #pragma unroll
        for (int it = 0; it < 3; ++it) {
            int i = tid + it * 256;
            if (i < 768) {
                int rr = i >> 6;
                int r = (rr < 3) ? rr : ((rr < 9) ? rr + 25 : rr + 50);
                *(bf16x4*)&xT[r][(i & 63) * 4] = z4;
            }
        }
        // zero a1T pad rows {0,1,27,28} + {29,30,56,57}: 8 rows x 32 bf16x4
        if (tid < 256) {
            int rr = tid >> 5;
            int r = (rr < 2) ? rr : ((rr < 6) ? rr + 25 : rr + 50);
            *(bf16x4*)&a1T[r][(tid & 31) * 4] = z4;
        }
    }
    __syncthreads();

    const int lane = tid & 63, wv = tid >> 6;
    const int m = lane & 15, q = lane >> 4;
    const bf16* xb  = &xT[m][q * 8];
    const bf16* a1b = &a1T[m][q * 8];

    // ================= conv0: Cin=256 (8 K-steps), K=7, pad=3 =================
    f32x4 acc[2][4] = {};
    {
        const bf16x8* A = (const bf16x8*)p0 + (size_t)wv * 64 + lane;
        #pragma unroll
        for (int k = 0; k < 7; ++k) {
            #pragma unroll
            for (int ks = 0; ks < 8; ++ks) {
                bf16x8 a0 = A[(k * 8 + ks) * 512];
                bf16x8 a1 = A[(k * 8 + ks) * 512 + 256];
                const bf16* pB = xb + k * XT_LD + ks * 32;
                bf16x8 bb0 = *(const bf16x8*)(pB);
                bf16x8 bb1 = *(const bf16x8*)(pB + 16 * XT_LD);
                bf16x8 bb2 = *(const bf16x8*)(pB + 31 * XT_LD);
                bf16x8 bb3 = *(const bf16x8*)(pB + 47 * XT_LD);
                acc[0][0] = __builtin_amdgcn_mfma_f32_16x16x32_bf16(a0, bb0, acc[0][0], 0, 0, 0);
                acc[0][1] = __builtin_amdgcn_mfma_f32_16x16x32_bf16(a0, bb1, acc[0][1], 0, 0, 0);
                acc[0][2] = __builtin_amdgcn_mfma_f32_16x16x32_bf16(a0, bb2, acc[0][2], 0, 0, 0);
                acc[0][3] = __builtin_amdgcn_mfma_f32_16x16x32_bf16(a0, bb3, acc[0][3], 0, 0, 0);
                acc[1][0] = __builtin_amdgcn_mfma_f32_16x16x32_bf16(a1, bb0, acc[1][0], 0, 0, 0);
                acc[1][1] = __builtin_amdgcn_mfma_f32_16x16x32_bf16(a1, bb1, acc[1][1], 0, 0, 0);
                acc[1][2] = __builtin_amdgcn_mfma_f32_16x16x32_bf16(a1, bb2, acc[1][2], 0, 0, 0);
                acc[1][3] = __builtin_amdgcn_mfma_f32_16x16x32_bf16(a1, bb3, acc[1][3], 0, 0, 0);
            }
        }
    }
    __syncthreads();   // xT dead; R0 may be reused (a2T)
    // zero a2T pad rows (R0), then conv0 epilogue -> a1T
    {
        bf16x4 z4 = {};
        int rr = tid >> 5;
        int r = (rr < 2) ? rr : ((rr < 6) ? rr + 25 : rr + 50);
        *(bf16x4*)&a2T[r][(tid & 31) * 4] = z4;
    }
    #pragma unroll
    for (int mt = 0; mt < 2; ++mt) {
        int co0 = (wv + 4 * mt) * 16 + q * 4;
        f32x4 bv = *(const f32x4*)&b0[co0];
        #pragma unroll
        for (int nt = 0; nt < 4; ++nt) {
            int l = (nt & 1) * 16 + m;
            if (l < 25) {
                bf16x4 v;
                #pragma unroll
                for (int r = 0; r < 4; ++r)
                    v[r] = (bf16)gelu_fast(acc[mt][nt][r] + bv[r]);
                *(bf16x4*)&a1T[l + 2 + 29 * (nt >> 1)][co0] = v;
            }
        }
    }
    __syncthreads();

    // ================= conv1: Cin=128 (4 K-steps), K=5, pad=2 =================
    f32x4 c1[2][4] = {};
    {
        const bf16x8* A = (const bf16x8*)p1 + (size_t)wv * 64 + lane;
        #pragma unroll
        for (int k = 0; k < 5; ++k) {
            #pragma unroll
            for (int ks = 0; ks < 4; ++ks) {
                bf16x8 a0 = A[(k * 4 + ks) * 512];
                bf16x8 a1 = A[(k * 4 + ks) * 512 + 256];
                const bf16* pB = a1b + k * A_LD + ks * 32;
                bf16x8 bb0 = *(const bf16x8*)(pB);
                bf16x8 bb1 = *(const bf16x8*)(pB + 16 * A_LD);
                bf16x8 bb2 = *(const bf16x8*)(pB + 29 * A_LD);
                bf16x8 bb3 = *(const bf16x8*)(pB + 45 * A_LD);
                c1[0][0] = __builtin_amdgcn_mfma_f32_16x16x32_bf16(a0, bb0, c1[0][0], 0, 0, 0);
                c1[0][1] = __builtin_amdgcn_mfma_f32_16x16x32_bf16(a0, bb1, c1[0][1], 0, 0, 0);
                c1[0][2] = __builtin_amdgcn_mfma_f32_16x16x32_bf16(a0, bb2, c1[0][2], 0, 0, 0);
                c1[0][3] = __builtin_amdgcn_mfma_f32_16x16x32_bf16(a0, bb3, c1[0][3], 0, 0, 0);
                c1[1][0] = __builtin_amdgcn_mfma_f32_16x16x32_bf16(a1, bb0, c1[1][0], 0, 0, 0);
                c1[1][1] = __builtin_amdgcn_mfma_f32_16x16x32_bf16(a1, bb1, c1[1][1], 0, 0, 0);
                c1[1][2] = __builtin_amdgcn_mfma_f32_16x16x32_bf16(a1, bb2, c1[1][2], 0, 0, 0);
                c1[1][3] = __builtin_amdgcn_mfma_f32_16x16x32_bf16(a1, bb3, c1[1][3], 0, 0, 0);
            }
        }
    }
    // epilogue -> a2T (R0; xT dead, disjoint from a1T reads)
    #pragma unroll
    for (int mt = 0; mt < 2; ++mt) {
        int co0 = (wv + 4 * mt) * 16 + q * 4;
        f32x4 bv = *(const f32x4*)&b1[co0];
        #pragma unroll
        for (int nt = 0; nt < 4; ++nt) {
            int l = (nt & 1) * 16 + m;
            if (l < 25) {
                bf16x4 v;
                #pragma unroll
                for (int r = 0; r < 4; ++r)
                    v[r] = (bf16)gelu_fast(c1[mt][nt][r] + bv[r]);
                *(bf16x4*)&a2T[l + 2 + 29 * (nt >> 1)][co0] = v;
            }
        }
    }
    __syncthreads();

    // ================= conv2: Cin=128 (4 K-steps), K=5, pad=2 =================
    f32x4 c2[2][4] = {};
    {
        const bf16* a2b = &a2T[m][q * 8];
        const bf16x8* A = (const bf16x8*)p2 + (size_t)wv * 64 + lane;
        #pragma unroll
        for (int k = 0; k < 5; ++k) {
            #pragma unroll
            for (int ks = 0; ks < 4; ++ks) {
                bf16x8 a0 = A[(k * 4 + ks) * 512];
                bf16x8 a1 = A[(k * 4 + ks) * 512 + 256];
                const bf16* pB = a2b + k * A_LD + ks * 32;
                bf16x8 bb0 = *(const bf16x8*)(pB);
                bf16x8 bb1 = *(const bf16x8*)(pB + 16 * A_LD);
                bf16x8 bb2 = *(const bf16x8*)(pB + 29 * A_LD);
                bf16x8 bb3 = *(const bf16x8*)(pB + 45 * A_LD);
                c2[0][0] = __builtin_amdgcn_mfma_f32_16x16x32_bf16(a0, bb0, c2[0][0], 0, 0, 0);
                c2[0][1] = __builtin_amdgcn_mfma_f32_16x16x32_bf16(a0, bb1, c2[0][1], 0, 0, 0);
                c2[0][2] = __builtin_amdgcn_mfma_f32_16x16x32_bf16(a0, bb2, c2[0][2], 0, 0, 0);
                c2[0][3] = __builtin_amdgcn_mfma_f32_16x16x32_bf16(a0, bb3, c2[0][3], 0, 0, 0);
                c2[1][0] = __builtin_amdgcn_mfma_f32_16x16x32_bf16(a1, bb0, c2[1][0], 0, 0, 0);
                c2[1][1] = __builtin_amdgcn_mfma_f32_16x16x32_bf16(a1, bb1, c2[1][1], 0, 0, 0);
                c2[1][2] = __builtin_amdgcn_mfma_f32_16x16x32_bf16(a1, bb2, c2[1][2], 0, 0, 0);
                c2[1][3] = __builtin_amdgcn_mfma_f32_16x16x32_bf16(a1, bb3, c2[1][3], 0, 0, 0);
            }
        }
    }
    // ===== register pooling: gelu + shuffle-reduce over l (lane bits 0-3) =====
    #pragma unroll
    for (int mt = 0; mt < 2; ++mt) {
        int co0 = (wv + 4 * mt) * 16 + q * 4;
        f32x4 bv = *(const f32x4*)&b2[co0];
        #pragma unroll
        for (int win = 0; win < 2; ++win) {
            f32x4 pool;
            #pragma unroll
            for (int r = 0; r < 4; ++r) {
                float s  = gelu_fast(c2[mt][2 * win][r] + bv[r]);       // l = m < 25
                float g1 = gelu_fast(c2[mt][2 * win + 1][r] + bv[r]);   // l = 16+m
                s += (m < 9) ? g1 : 0.0f;
                s += __shfl_xor(s, 1);
                s += __shfl_xor(s, 2);
                s += __shfl_xor(s, 4);
                s += __shfl_xor(s, 8);
                pool[r] = s * 0.04f;
            }
            if (m == 0) *(f32x4*)&feat[win * 128 + co0] = pool;
        }
    }
    __syncthreads();

    // ================= head (both windows, all 256 threads) =================
    {
        int win = tid >> 7, co = tid & 127;
        const bf16x8* row = (const bf16x8*)(hw1b + co * H);
        const float* f = feat + win * 128;
        float a = hb1[co];
        #pragma unroll
        for (int jv = 0; jv < 16; ++jv) {
            bf16x8 w8 = row[jv];
            #pragma unroll
            for (int u = 0; u < 8; ++u)
                a += (float)w8[u] * f[jv * 8 + u];
        }
        hbuf[tid] = gelu_fast(a);
    }
    __syncthreads();

    if (tid < 128) {
        int win = tid >> 6, j = tid & 63;     // wave 0 -> win 0, wave 1 -> win 1
        const float* hb = hbuf + win * 128;
        float p = hw2[j] * hb[j] + hw2[j + 64] * hb[j + 64];
        #pragma unroll
        for (int off = 32; off > 0; off >>= 1) p += __shfl_down(p, off);
        if (j == 0) {
            float z = p + hb2[0];
            scores_tmp[b * NW + w0 + win] = 5.0f / (1.0f + expf(-z));
        }
    }
}

// ---------------------------------------------------------------------------
__global__ void finalize_kernel(const float* __restrict__ tmp, float* __restrict__ out) {
    int w = blockIdx.x * 256 + threadIdx.x;
    if (w < NW) {
        float s = 0.0f;
        #pragma unroll
        for (int b = 0; b < BATCH; ++b) s += tmp[b * NW + w];
        s *= 0.125f;
        out[w] = s;
        out[NW + w] = (s < 3.5f) ? 1.0f : 0.0f;
    }
}

// ---------------------------------------------------------------------------
extern "C" void kernel_launch(void* const* d_in, const int* in_sizes, int n_in,
                              void* d_out, int out_size, void* d_ws, size_t ws_size,
                              hipStream_t stream) {
    const float* lat  = (const float*)d_in[0];
    const float* c0w  = (const float*)d_in[1];
    const float* c0b  = (const float*)d_in[2];
    const float* c1w  = (const float*)d_in[3];
    const float* c1b  = (const float*)d_in[4];
    const float* c2w  = (const float*)d_in[5];
    const float* c2b  = (const float*)d_in[6];
    const float* hw1  = (const float*)d_in[7];
    const float* hb1  = (const float*)d_in[8];
    const float* hw2  = (const float*)d_in[9];
    const float* hb2  = (const float*)d_in[10];

    // workspace layout
    bf16* p0   = (bf16*)d_ws;                                 // 458752 B
    bf16* p1   = (bf16*)((char*)d_ws + 458752);               // 163840 B
    bf16* p2   = (bf16*)((char*)d_ws + 622592);               // 163840 B
    bf16* hw1b = (bf16*)((char*)d_ws + 786432);               //  32768 B
    float* tmp = (float*)((char*)d_ws + 819200);              //  32000 B

    const int n0 = 128 * 256 * 7;  // 229376
    const int n1 = 128 * 128 * 5;  //  81920
    repack_w<<<(n0 + 255) / 256, 256, 0, stream>>>(c0w, p0, 256, 7, 8, n0);
    repack_w<<<(n1 + 255) / 256, 256, 0, stream>>>(c1w, p1, 128, 5, 4, n1);
    repack_w<<<(n1 + 255) / 256, 256, 0, stream>>>(c2w, p2, 128, 5, 4, n1);
    cvt_bf16<<<64, 256, 0, stream>>>(hw1, hw1b, 128 * 128);

    critic_kernel<<<BATCH * (NW / 2), 256, 0, stream>>>(lat, p0, c0b, p1, c1b, p2, c2b,
                                                        hw1b, hb1, hw2, hb2, tmp);
    finalize_kernel<<<4, 256, 0, stream>>>(tmp, (float*)d_out);
}